// Round 3
// baseline (303.798 us; speedup 1.0000x reference)
//
#include <hip/hip_runtime.h>
#include <stdint.h>

#define D_MODEL 1024
#define NHEAD 16
#define HDIM 64
#define BATCH 4
#define SEQ 2048
#define BS (BATCH*SEQ)      // 8192 rows
#define NQKV (3*D_MODEL)    // 3072
#define BHEADS (BATCH*NHEAD) // 64

typedef __bf16 bf16x8 __attribute__((ext_vector_type(8)));
typedef __bf16 bf16x2 __attribute__((ext_vector_type(2)));
typedef float f32x4 __attribute__((ext_vector_type(4)));
typedef float f32x2 __attribute__((ext_vector_type(2)));

__device__ __forceinline__ unsigned short f2bf(float f) {
    union { __bf16 b; unsigned short s; } u; u.b = (__bf16)f; return u.s;
}
__device__ __forceinline__ float bf2f(unsigned short b) {
    union { unsigned u; float f; } v; v.u = ((unsigned)b) << 16;
    return v.f;
}
__device__ __forceinline__ unsigned pack_bf16(float a, float b) {
    f32x2 t; t[0] = a; t[1] = b;
    bf16x2 r = __builtin_convertvector(t, bf16x2);
    union { bf16x2 v; unsigned u; } u; u.v = r; return u.u;
}

typedef __attribute__((address_space(3))) void lds_void_t;
typedef const __attribute__((address_space(1))) void glb_void_t;
__device__ __forceinline__ void gl2lds16(const void* g, void* l) {
    __builtin_amdgcn_global_load_lds((glb_void_t*)g, (lds_void_t*)l, 16, 0, 0);
}

// ---------------- x f32 -> bf16 ----------------
__global__ __launch_bounds__(256) void k_cvt_x(const float4* __restrict__ x,
                                               uint2* __restrict__ o) {
    int i = blockIdx.x * 256 + threadIdx.x;
    float4 v = x[i];
    uint2 r;
    r.x = (unsigned)f2bf(v.x) | ((unsigned)f2bf(v.y) << 16);
    r.y = (unsigned)f2bf(v.z) | ((unsigned)f2bf(v.w) << 16);
    o[i] = r;
}

// ------------- weight transpose: in[K=1024][ndim] f32 -> out[ndim][1024] bf16 -------------
__global__ __launch_bounds__(256) void k_transpose(const float* __restrict__ in,
                                                   unsigned short* __restrict__ out,
                                                   int ndim) {
    __shared__ float tile[64][65];
    const int n0 = blockIdx.x * 64, k0 = blockIdx.y * 64, tid = threadIdx.x;
#pragma unroll
    for (int i = 0; i < 16; i++) {
        int f = i * 256 + tid; int r = f >> 6, c = f & 63;
        tile[r][c] = in[(size_t)(k0 + r) * ndim + n0 + c];
    }
    __syncthreads();
#pragma unroll
    for (int i = 0; i < 16; i++) {
        int f = i * 256 + tid; int n = f >> 6, kq = f & 63;
        out[(size_t)(n0 + n) * 1024 + k0 + kq] = f2bf(tile[kq][n]);
    }
}

// ---------------- GEMM: C[M][N] = A[M][1024] * Bt[N][1024]^T (bf16 in, f32 acc) ----------------
// global_load_lds staging (m97 pattern): linear LDS tiles, wave-uniform base + lane*16B.
// MODE 0: qkv epilogue -> q[bh][s][64], k[bh][s][64], v[bh][s][64] (all coalesced)
// MODE 1: plain f32 C write (N assumed 1024)
template<int MODE>
__global__ __launch_bounds__(256) void k_gemm(const unsigned short* __restrict__ A,
                                              const unsigned short* __restrict__ Bt,
                                              float* __restrict__ Cout,
                                              unsigned short* __restrict__ qo,
                                              unsigned short* __restrict__ ko,
                                              unsigned short* __restrict__ vo) {
    __shared__ __align__(16) unsigned short As[128 * 64];
    __shared__ __align__(16) unsigned short Bs[128 * 64];
    const int tid = threadIdx.x, lane = tid & 63, wid = tid >> 6;
    const int l16 = lane & 15, lq = lane >> 4;
    const int wr = wid >> 1, wc = wid & 1;
    const int M0 = blockIdx.x * 128, N0 = blockIdx.y * 128;

    f32x4 acc[4][4] = {};

    for (int k0 = 0; k0 < 1024; k0 += 64) {
#pragma unroll
        for (int i = 0; i < 4; i++) {
            int ch = i * 256 + tid;                 // per-lane chunk index
            int r = ch >> 3, c = (ch & 7) * 8;
            int ldsbase = (i * 256 + wid * 64) * 8; // wave-uniform element offset
            gl2lds16(A  + (size_t)(M0 + r) * 1024 + k0 + c, &As[ldsbase]);
            gl2lds16(Bt + (size_t)(N0 + r) * 1024 + k0 + c, &Bs[ldsbase]);
        }
        __syncthreads();   // drains vmcnt(0) -> global_load_lds landed
#pragma unroll
        for (int kk = 0; kk < 2; kk++) {
            bf16x8 af[4], bfr[4];
#pragma unroll
            for (int m = 0; m < 4; m++)
                af[m] = *(const bf16x8*)&As[(wr * 64 + m * 16 + l16) * 64 + kk * 32 + lq * 8];
#pragma unroll
            for (int n = 0; n < 4; n++)
                bfr[n] = *(const bf16x8*)&Bs[(wc * 64 + n * 16 + l16) * 64 + kk * 32 + lq * 8];
#pragma unroll
            for (int m = 0; m < 4; m++)
#pragma unroll
                for (int n = 0; n < 4; n++)
                    acc[m][n] = __builtin_amdgcn_mfma_f32_16x16x32_bf16(af[m], bfr[n], acc[m][n], 0, 0, 0);
        }
        __syncthreads();
    }

#pragma unroll
    for (int m = 0; m < 4; m++) {
#pragma unroll
        for (int n = 0; n < 4; n++) {
#pragma unroll
            for (int r = 0; r < 4; r++) {
                int row = M0 + wr * 64 + m * 16 + lq * 4 + r;
                int col = N0 + wc * 64 + n * 16 + l16;
                float val = acc[m][n][r];
                if (MODE == 1) {
                    Cout[(size_t)row * 1024 + col] = val;
                } else {
                    int which = col >> 10, h = (col >> 6) & 15, d = col & 63;
                    int b = row >> 11, s = row & 2047, bh = (b << 4) + h;
                    unsigned short bv = f2bf(val);
                    size_t off = ((size_t)bh * SEQ + s) * 64 + d;
                    if (which == 0)      qo[off] = bv;
                    else if (which == 1) ko[off] = bv;
                    else                 vo[off] = bv;
                }
            }
        }
    }
}

// ---------------- v[bh][s][64] -> vT[bh][d][s] (coalesced LDS transpose) ----------------
__global__ __launch_bounds__(256) void k_vtr(const unsigned short* __restrict__ v,
                                             unsigned short* __restrict__ vt) {
    __shared__ __align__(16) unsigned short tile[64][70];
    const int tid = threadIdx.x;
    const int s0 = blockIdx.x * 64, bh = blockIdx.y;
    const unsigned short* src = v + ((size_t)bh * SEQ + s0) * 64;
#pragma unroll
    for (int i = 0; i < 2; i++) {
        int ch = i * 256 + tid; int r = ch >> 3, c = (ch & 7) * 8;
        *(bf16x8*)&tile[r][c] = *(const bf16x8*)(src + r * 64 + c);
    }
    __syncthreads();
    unsigned short* dst = vt + (size_t)bh * 64 * SEQ + s0;
#pragma unroll
    for (int i = 0; i < 2; i++) {
        int ch = i * 256 + tid; int d = ch >> 3, sc = (ch & 7) * 8;
        ushort4 a, b;
        a.x = tile[sc + 0][d]; a.y = tile[sc + 1][d];
        a.z = tile[sc + 2][d]; a.w = tile[sc + 3][d];
        b.x = tile[sc + 4][d]; b.y = tile[sc + 5][d];
        b.z = tile[sc + 6][d]; b.w = tile[sc + 7][d];
        *(ushort4*)(dst + (size_t)d * SEQ + sc) = a;
        *(ushort4*)(dst + (size_t)d * SEQ + sc + 4) = b;
    }
}

// ---------------- per-head LayerNorm on q,k (in place, bf16) ----------------
// q rows additionally scaled by log2(e)/8 so flash softmax runs in exp2 domain.
__global__ __launch_bounds__(256) void k_ln(unsigned short* __restrict__ q,
                                            unsigned short* __restrict__ k,
                                            const float* __restrict__ qg, const float* __restrict__ qb,
                                            const float* __restrict__ kg, const float* __restrict__ kb) {
    const int wid = threadIdx.x >> 6, lane = threadIdx.x & 63;
    size_t row = (size_t)blockIdx.x * 4 + wid;
    unsigned short* p = blockIdx.y ? k : q;
    const float* g  = blockIdx.y ? kg : qg;
    const float* bb = blockIdx.y ? kb : qb;
    const float c = blockIdx.y ? 1.0f : 0.18033688011112042f;  // log2(e)/8 folded into q
    float v = bf2f(p[row * 64 + lane]);
    float s = v;
#pragma unroll
    for (int m = 32; m; m >>= 1) s += __shfl_xor(s, m);
    float mean = s * (1.0f / 64.0f);
    float d = v - mean, sq = d * d;
#pragma unroll
    for (int m = 32; m; m >>= 1) sq += __shfl_xor(sq, m);
    float rs = rsqrtf(sq * (1.0f / 64.0f) + 1e-5f);
    p[row * 64 + lane] = f2bf((d * rs * g[lane] + bb[lane]) * c);
}

// ---------------- flash attention: dbuf K/V, async-STAGE split, 1 barrier/tile ----------------
// q[bh][s][64] (pre-scaled), k[bh][s][64], vT[bh][d][s] -> aout[b*S+s][h*64+d] bf16
// S^T = mfma(A=K, B=Q): lane owns q-row n=l16, kv rows m = nb*16 + lq*4 + r.
// O^T = mfma(A=V^T, B=P): P repacked via per-wave LDS strip (intra-wave, no barrier).
__global__ __launch_bounds__(256) void k_flash(const unsigned short* __restrict__ q,
                                               const unsigned short* __restrict__ k,
                                               const unsigned short* __restrict__ vt,
                                               unsigned short* __restrict__ aout) {
    __shared__ __align__(16) unsigned short Ks[2][64][72];
    __shared__ __align__(16) unsigned short Vs[2][64][72];
    __shared__ __align__(16) unsigned short Ps[4][16][72];
    const int tid = threadIdx.x, lane = tid & 63, wid = tid >> 6;
    const int l16 = lane & 15, lq = lane >> 4;
    const int bh = blockIdx.y;
    const int q0 = blockIdx.x * 64 + wid * 16;

    bf16x8 bq[2];
#pragma unroll
    for (int kk = 0; kk < 2; kk++)
        bq[kk] = *(const bf16x8*)(q + ((size_t)bh * SEQ + q0 + l16) * 64 + kk * 32 + lq * 8);

    // staging descriptors: thread handles chunks ch = i*256 + tid, i=0,1
    int rr[2], cc[2];
    const unsigned short* kp[2];
    const unsigned short* vp[2];
#pragma unroll
    for (int i = 0; i < 2; i++) {
        int ch = i * 256 + tid;
        rr[i] = ch >> 3; cc[i] = (ch & 7) * 8;
        kp[i] = k  + (size_t)bh * SEQ * 64 + (size_t)rr[i] * 64  + cc[i];
        vp[i] = vt + (size_t)bh * 64 * SEQ + (size_t)rr[i] * SEQ + cc[i];
    }

    // prologue: stage tile 0 into buffer 0
    bf16x8 kr[2], vr[2];
#pragma unroll
    for (int i = 0; i < 2; i++) {
        kr[i] = *(const bf16x8*)kp[i]; vr[i] = *(const bf16x8*)vp[i];
        kp[i] += 64 * 64; vp[i] += 64;
    }
#pragma unroll
    for (int i = 0; i < 2; i++) {
        *(bf16x8*)&Ks[0][rr[i]][cc[i]] = kr[i];
        *(bf16x8*)&Vs[0][rr[i]][cc[i]] = vr[i];
    }
    __syncthreads();

    f32x4 o[4] = {};
    float m_run = -1e30f, l_run = 0.f;

    for (int t = 0; t < SEQ / 64; t++) {
        const int cur = t & 1;
        const bool more = (t + 1) < SEQ / 64;
        // issue next-tile global loads early; latency hides under QK/softmax/PV
        if (more) {
#pragma unroll
            for (int i = 0; i < 2; i++) {
                kr[i] = *(const bf16x8*)kp[i]; vr[i] = *(const bf16x8*)vp[i];
                kp[i] += 64 * 64; vp[i] += 64;
            }
        }

        // S^T block: sa[nb][r] = S'[q=l16][kv = t*64 + nb*16 + lq*4 + r]  (log2 domain)
        f32x4 sa[4] = {};
        __builtin_amdgcn_s_setprio(1);
#pragma unroll
        for (int kk = 0; kk < 2; kk++) {
#pragma unroll
            for (int nb = 0; nb < 4; nb++) {
                bf16x8 ak = *(const bf16x8*)&Ks[cur][nb * 16 + l16][kk * 32 + lq * 8];
                sa[nb] = __builtin_amdgcn_mfma_f32_16x16x32_bf16(ak, bq[kk], sa[nb], 0, 0, 0);
            }
        }
        __builtin_amdgcn_s_setprio(0);

        // row max: 16 in-register values + 2 cross-lq shuffles
        float mx = fmaxf(fmaxf(sa[0][0], sa[0][1]), fmaxf(sa[0][2], sa[0][3]));
#pragma unroll
        for (int nb = 1; nb < 4; nb++)
            mx = fmaxf(mx, fmaxf(fmaxf(sa[nb][0], sa[nb][1]), fmaxf(sa[nb][2], sa[nb][3])));
        mx = fmaxf(mx, __shfl_xor(mx, 16));
        mx = fmaxf(mx, __shfl_xor(mx, 32));

        // defer-max (T13): only rescale when max grew by > 8 (log2 units -> P <= 256)
        if (!__all(mx <= m_run + 8.0f)) {
            float mn = fmaxf(m_run, mx);
            float sc = __builtin_amdgcn_exp2f(m_run - mn);
#pragma unroll
            for (int db = 0; db < 4; db++) o[db] *= sc;
            l_run *= sc;
            m_run = mn;
        }

        // P = exp2(S' - m_run), packed to bf16 pairs
        float rs = 0.f;
        unsigned w[4][2];
#pragma unroll
        for (int nb = 0; nb < 4; nb++) {
            float p0 = __builtin_amdgcn_exp2f(sa[nb][0] - m_run);
            float p1 = __builtin_amdgcn_exp2f(sa[nb][1] - m_run);
            float p2 = __builtin_amdgcn_exp2f(sa[nb][2] - m_run);
            float p3 = __builtin_amdgcn_exp2f(sa[nb][3] - m_run);
            rs += (p0 + p1) + (p2 + p3);
            w[nb][0] = pack_bf16(p0, p1);
            w[nb][1] = pack_bf16(p2, p3);
        }
        rs += __shfl_xor(rs, 16);
        rs += __shfl_xor(rs, 32);
        l_run += rs;

        // redistribute P within the wave via per-wave LDS strip (no barrier needed;
        // DS ops from one wave complete in order). Fence stops TBAA reordering.
#pragma unroll
        for (int nb = 0; nb < 4; nb++)
            *(uint2*)&Ps[wid][l16][nb * 16 + lq * 4] = make_uint2(w[nb][0], w[nb][1]);
        asm volatile("" ::: "memory");
        bf16x8 bp[2];
        bp[0] = *(const bf16x8*)&Ps[wid][l16][lq * 8];
        bp[1] = *(const bf16x8*)&Ps[wid][l16][32 + lq * 8];

        // O^T += V^T * P
        __builtin_amdgcn_s_setprio(1);
#pragma unroll
        for (int kk = 0; kk < 2; kk++) {
#pragma unroll
            for (int db = 0; db < 4; db++) {
                bf16x8 av = *(const bf16x8*)&Vs[cur][db * 16 + l16][kk * 32 + lq * 8];
                o[db] = __builtin_amdgcn_mfma_f32_16x16x32_bf16(av, bp[kk], o[db], 0, 0, 0);
            }
        }
        __builtin_amdgcn_s_setprio(0);

        // write next tile into the other buffer (vmcnt wait lands here, after compute)
        if (more) {
#pragma unroll
            for (int i = 0; i < 2; i++) {
                *(bf16x8*)&Ks[cur ^ 1][rr[i]][cc[i]] = kr[i];
                *(bf16x8*)&Vs[cur ^ 1][rr[i]][cc[i]] = vr[i];
            }
        }
        __syncthreads();
    }

    float inv = 1.0f / l_run;
    const int b = bh >> 4, h = bh & 15;
#pragma unroll
    for (int db = 0; db < 4; db++) {
        ushort4 u4;
        u4.x = f2bf(o[db][0] * inv);
        u4.y = f2bf(o[db][1] * inv);
        u4.z = f2bf(o[db][2] * inv);
        u4.w = f2bf(o[db][3] * inv);
        *(ushort4*)(aout + ((size_t)b * SEQ + q0 + l16) * 1024 + h * 64 + db * 16 + lq * 4) = u4;
    }
}

extern "C" void kernel_launch(void* const* d_in, const int* in_sizes, int n_in,
                              void* d_out, int out_size, void* d_ws, size_t ws_size,
                              hipStream_t stream) {
    const float* x     = (const float*)d_in[0];
    const float* wqkv  = (const float*)d_in[1];
    const float* wproj = (const float*)d_in[2];
    const float* qg    = (const float*)d_in[3];
    const float* qb    = (const float*)d_in[4];
    const float* kg    = (const float*)d_in[5];
    const float* kb    = (const float*)d_in[6];
    float* out = (float*)d_out;

    char* ws = (char*)d_ws;
    unsigned short* xbf    = (unsigned short*)(ws);                       // 16 MB (reused for vT)
    unsigned short* wqkvT  = (unsigned short*)(ws + (16llu << 20));       // 6 MB
    unsigned short* wprojT = (unsigned short*)(ws + (22llu << 20));       // 2 MB
    unsigned short* qraw   = (unsigned short*)(ws + (24llu << 20));       // 16 MB
    unsigned short* kraw   = (unsigned short*)(ws + (40llu << 20));       // 16 MB
    unsigned short* vraw   = (unsigned short*)(ws + (56llu << 20));       // 16 MB
    unsigned short* aattn  = (unsigned short*)(ws + (72llu << 20));       // 16 MB (total 88 MB)
    unsigned short* vtr    = xbf;   // xbf is dead after k_gemm<0>; reuse for vT

    hipLaunchKernelGGL(k_cvt_x, dim3(8192), dim3(256), 0, stream, (const float4*)x, (uint2*)xbf);
    hipLaunchKernelGGL(k_transpose, dim3(48, 16), dim3(256), 0, stream, wqkv, wqkvT, 3072);
    hipLaunchKernelGGL(k_transpose, dim3(16, 16), dim3(256), 0, stream, wproj, wprojT, 1024);
    hipLaunchKernelGGL((k_gemm<0>), dim3(64, 24), dim3(256), 0, stream, xbf, wqkvT, (float*)nullptr, qraw, kraw, vraw);
    hipLaunchKernelGGL(k_ln, dim3(32768, 2), dim3(256), 0, stream, qraw, kraw, qg, qb, kg, kb);
    hipLaunchKernelGGL(k_vtr, dim3(32, 64), dim3(256), 0, stream, vraw, vtr);
    hipLaunchKernelGGL(k_flash, dim3(32, 64), dim3(256), 0, stream, qraw, kraw, vtr, aattn);
    hipLaunchKernelGGL((k_gemm<1>), dim3(64, 8), dim3(256), 0, stream, aattn, wprojT, out,
                       (unsigned short*)nullptr, (unsigned short*)nullptr, (unsigned short*)nullptr);
}

// Round 4
// 257.970 us; speedup vs baseline: 1.1777x; 1.1777x over previous
//
#include <hip/hip_runtime.h>
#include <stdint.h>

#define D_MODEL 1024
#define NHEAD 16
#define HDIM 64
#define BATCH 4
#define SEQ 2048
#define BS (BATCH*SEQ)      // 8192 rows
#define NQKV (3*D_MODEL)    // 3072
#define BHEADS (BATCH*NHEAD) // 64

typedef __bf16 bf16x8 __attribute__((ext_vector_type(8)));
typedef __bf16 bf16x2 __attribute__((ext_vector_type(2)));
typedef float f32x4 __attribute__((ext_vector_type(4)));
typedef float f32x2 __attribute__((ext_vector_type(2)));
typedef float f32x16 __attribute__((ext_vector_type(16)));

__device__ __forceinline__ unsigned short f2bf(float f) {
    union { __bf16 b; unsigned short s; } u; u.b = (__bf16)f; return u.s;
}
__device__ __forceinline__ float bf2f(unsigned short b) {
    union { unsigned u; float f; } v; v.u = ((unsigned)b) << 16;
    return v.f;
}
__device__ __forceinline__ unsigned pack_bf16(float a, float b) {
    f32x2 t; t[0] = a; t[1] = b;
    bf16x2 r = __builtin_convertvector(t, bf16x2);
    union { bf16x2 v; unsigned u; } u; u.v = r; return u.u;
}

typedef __attribute__((address_space(3))) void lds_void_t;
typedef const __attribute__((address_space(1))) void glb_void_t;
__device__ __forceinline__ void gl2lds16(const void* g, void* l) {
    __builtin_amdgcn_global_load_lds((glb_void_t*)g, (lds_void_t*)l, 16, 0, 0);
}

// ---------------- x f32 -> bf16 ----------------
__global__ __launch_bounds__(256) void k_cvt_x(const float4* __restrict__ x,
                                               uint2* __restrict__ o) {
    int i = blockIdx.x * 256 + threadIdx.x;
    float4 v = x[i];
    uint2 r;
    r.x = (unsigned)f2bf(v.x) | ((unsigned)f2bf(v.y) << 16);
    r.y = (unsigned)f2bf(v.z) | ((unsigned)f2bf(v.w) << 16);
    o[i] = r;
}

// ------------- weight transpose: in[K=1024][ndim] f32 -> out[ndim][1024] bf16 -------------
__global__ __launch_bounds__(256) void k_transpose(const float* __restrict__ in,
                                                   unsigned short* __restrict__ out,
                                                   int ndim) {
    __shared__ float tile[64][65];
    const int n0 = blockIdx.x * 64, k0 = blockIdx.y * 64, tid = threadIdx.x;
#pragma unroll
    for (int i = 0; i < 16; i++) {
        int f = i * 256 + tid; int r = f >> 6, c = f & 63;
        tile[r][c] = in[(size_t)(k0 + r) * ndim + n0 + c];
    }
    __syncthreads();
#pragma unroll
    for (int i = 0; i < 16; i++) {
        int f = i * 256 + tid; int n = f >> 6, kq = f & 63;
        out[(size_t)(n0 + n) * 1024 + k0 + kq] = f2bf(tile[kq][n]);
    }
}

// ---------------- GEMM: C[M][N] = A[M][1024] * Bt[N][1024]^T (bf16 in, f32 acc) ----------------
// MODE 0: qkv epilogue -> q[bh][s][64], k[bh][s][64], v[bh][s][64] (all coalesced)
// MODE 1: plain f32 C write (N assumed 1024)
template<int MODE>
__global__ __launch_bounds__(256) void k_gemm(const unsigned short* __restrict__ A,
                                              const unsigned short* __restrict__ Bt,
                                              float* __restrict__ Cout,
                                              unsigned short* __restrict__ qo,
                                              unsigned short* __restrict__ ko,
                                              unsigned short* __restrict__ vo) {
    __shared__ __align__(16) unsigned short As[128 * 64];
    __shared__ __align__(16) unsigned short Bs[128 * 64];
    const int tid = threadIdx.x, lane = tid & 63, wid = tid >> 6;
    const int l16 = lane & 15, lq = lane >> 4;
    const int wr = wid >> 1, wc = wid & 1;
    const int M0 = blockIdx.x * 128, N0 = blockIdx.y * 128;

    f32x4 acc[4][4] = {};

    for (int k0 = 0; k0 < 1024; k0 += 64) {
#pragma unroll
        for (int i = 0; i < 4; i++) {
            int ch = i * 256 + tid;
            int r = ch >> 3, c = (ch & 7) * 8;
            int ldsbase = (i * 256 + wid * 64) * 8;
            gl2lds16(A  + (size_t)(M0 + r) * 1024 + k0 + c, &As[ldsbase]);
            gl2lds16(Bt + (size_t)(N0 + r) * 1024 + k0 + c, &Bs[ldsbase]);
        }
        __syncthreads();
#pragma unroll
        for (int kk = 0; kk < 2; kk++) {
            bf16x8 af[4], bfr[4];
#pragma unroll
            for (int m = 0; m < 4; m++)
                af[m] = *(const bf16x8*)&As[(wr * 64 + m * 16 + l16) * 64 + kk * 32 + lq * 8];
#pragma unroll
            for (int n = 0; n < 4; n++)
                bfr[n] = *(const bf16x8*)&Bs[(wc * 64 + n * 16 + l16) * 64 + kk * 32 + lq * 8];
#pragma unroll
            for (int m = 0; m < 4; m++)
#pragma unroll
                for (int n = 0; n < 4; n++)
                    acc[m][n] = __builtin_amdgcn_mfma_f32_16x16x32_bf16(af[m], bfr[n], acc[m][n], 0, 0, 0);
        }
        __syncthreads();
    }

#pragma unroll
    for (int m = 0; m < 4; m++) {
#pragma unroll
        for (int n = 0; n < 4; n++) {
#pragma unroll
            for (int r = 0; r < 4; r++) {
                int row = M0 + wr * 64 + m * 16 + lq * 4 + r;
                int col = N0 + wc * 64 + n * 16 + l16;
                float val = acc[m][n][r];
                if (MODE == 1) {
                    Cout[(size_t)row * 1024 + col] = val;
                } else {
                    int which = col >> 10, h = (col >> 6) & 15, d = col & 63;
                    int b = row >> 11, s = row & 2047, bh = (b << 4) + h;
                    unsigned short bv = f2bf(val);
                    size_t off = ((size_t)bh * SEQ + s) * 64 + d;
                    if (which == 0)      qo[off] = bv;
                    else if (which == 1) ko[off] = bv;
                    else                 vo[off] = bv;
                }
            }
        }
    }
}

// ---------------- v[bh][s][64] -> vT[bh][d][s] (coalesced LDS transpose) ----------------
__global__ __launch_bounds__(256) void k_vtr(const unsigned short* __restrict__ v,
                                             unsigned short* __restrict__ vt) {
    __shared__ __align__(16) unsigned short tile[64][70];
    const int tid = threadIdx.x;
    const int s0 = blockIdx.x * 64, bh = blockIdx.y;
    const unsigned short* src = v + ((size_t)bh * SEQ + s0) * 64;
#pragma unroll
    for (int i = 0; i < 2; i++) {
        int ch = i * 256 + tid; int r = ch >> 3, c = (ch & 7) * 8;
        *(bf16x8*)&tile[r][c] = *(const bf16x8*)(src + r * 64 + c);
    }
    __syncthreads();
    unsigned short* dst = vt + (size_t)bh * 64 * SEQ + s0;
#pragma unroll
    for (int i = 0; i < 2; i++) {
        int ch = i * 256 + tid; int d = ch >> 3, sc = (ch & 7) * 8;
        ushort4 a, b;
        a.x = tile[sc + 0][d]; a.y = tile[sc + 1][d];
        a.z = tile[sc + 2][d]; a.w = tile[sc + 3][d];
        b.x = tile[sc + 4][d]; b.y = tile[sc + 5][d];
        b.z = tile[sc + 6][d]; b.w = tile[sc + 7][d];
        *(ushort4*)(dst + (size_t)d * SEQ + sc) = a;
        *(ushort4*)(dst + (size_t)d * SEQ + sc + 4) = b;
    }
}

// ---------------- per-head LayerNorm on q,k (in place, bf16) ----------------
// q rows additionally scaled by log2(e)/8 so flash softmax runs in exp2 domain.
__global__ __launch_bounds__(256) void k_ln(unsigned short* __restrict__ q,
                                            unsigned short* __restrict__ k,
                                            const float* __restrict__ qg, const float* __restrict__ qb,
                                            const float* __restrict__ kg, const float* __restrict__ kb) {
    const int wid = threadIdx.x >> 6, lane = threadIdx.x & 63;
    size_t row = (size_t)blockIdx.x * 4 + wid;
    unsigned short* p = blockIdx.y ? k : q;
    const float* g  = blockIdx.y ? kg : qg;
    const float* bb = blockIdx.y ? kb : qb;
    const float c = blockIdx.y ? 1.0f : 0.18033688011112042f;  // log2(e)/8 folded into q
    float v = bf2f(p[row * 64 + lane]);
    float s = v;
#pragma unroll
    for (int m = 32; m; m >>= 1) s += __shfl_xor(s, m);
    float mean = s * (1.0f / 64.0f);
    float d = v - mean, sq = d * d;
#pragma unroll
    for (int m = 32; m; m >>= 1) sq += __shfl_xor(sq, m);
    float rs = rsqrtf(sq * (1.0f / 64.0f) + 1e-5f);
    p[row * 64 + lane] = f2bf((d * rs * g[lane] + bb[lane]) * c);
}

// ---------------- flash attention, 32x32 MFMA + permlane P-exchange ----------------
// q[bh][s][64] (pre-scaled), k[bh][s][64], vT[bh][d][s] -> aout[b*S+s][h*64+d] bf16
// Wave owns 32 q-rows (col=lane&31). S^T = mfma32(A=K, B=Q) -> lane holds 32 P values
// for ONE q. P->PV B-frag exchange is a pure lane<->lane+32 half-swap: v_permlane32_swap.
// K/V tiles [64][64] in LDS, granule-XOR-swizzled via pre-swizzled gl2lds SOURCE addrs.
__global__ __launch_bounds__(256, 4) void k_flash(const unsigned short* __restrict__ q,
                                                  const unsigned short* __restrict__ k,
                                                  const unsigned short* __restrict__ vt,
                                                  unsigned short* __restrict__ aout) {
    __shared__ __align__(16) unsigned short Ks[2][64 * 64];
    __shared__ __align__(16) unsigned short Vs[2][64 * 64];
    const int tid = threadIdx.x, lane = tid & 63, wid = tid >> 6;
    const int l32 = lane & 31, hi = lane >> 5;
    const int bh = blockIdx.x;                 // bh fastest -> q-blocks of one bh share an XCD
    const int q0 = blockIdx.y * 128 + wid * 32;

    // Q B-frags: bq[t] = Q[q0+l32][t*16 + hi*8 .. +7]
    const unsigned short* qrow = q + ((size_t)bh * SEQ + q0 + l32) * 64 + hi * 8;
    bf16x8 bq[4];
#pragma unroll
    for (int t = 0; t < 4; t++)
        bq[t] = *(const bf16x8*)(qrow + t * 16);

    // staging: thread covers granule slots s = i*256+tid (16B granules, 8/row).
    // gl2lds dest is linear (wave-uniform base + lane*16); logical granule (row, gd)
    // lives at phys granule gd^(row&7)  =>  pre-swizzle the SOURCE address instead.
    const unsigned short* kp[2];
    const unsigned short* vp[2];
#pragma unroll
    for (int i = 0; i < 2; i++) {
        int s = i * 256 + tid;
        int row = s >> 3, gsrc = (s & 7) ^ (row & 7);
        kp[i] = k  + (size_t)bh * SEQ * 64 + (size_t)row * 64  + gsrc * 8;
        vp[i] = vt + (size_t)bh * 64 * SEQ + (size_t)row * SEQ + gsrc * 8;
    }
    // prologue: stage tile 0 into buf 0
#pragma unroll
    for (int i = 0; i < 2; i++) {
        int ldsoff = (i * 256 + wid * 64) * 8;  // wave-uniform (elements)
        gl2lds16(kp[i], &Ks[0][ldsoff]);
        gl2lds16(vp[i], &Vs[0][ldsoff]);
        kp[i] += 64 * 64; vp[i] += 64;
    }
    __syncthreads();

    f32x16 o0 = {}, o1 = {};
    float m_run = -1e30f, l_run = 0.f;
    const int xs = (l32 & 7);                  // row-XOR key (same for row and row+32)

    for (int t = 0; t < SEQ / 64; t++) {
        const int cur = t & 1;
        if (t + 1 < SEQ / 64) {               // issue next-tile staging; drains at barrier
#pragma unroll
            for (int i = 0; i < 2; i++) {
                int ldsoff = (i * 256 + wid * 64) * 8;
                gl2lds16(kp[i], &Ks[cur ^ 1][ldsoff]);
                gl2lds16(vp[i], &Vs[cur ^ 1][ldsoff]);
                kp[i] += 64 * 64; vp[i] += 64;
            }
        }

        // S^T: sa0 = kv rows 0..31, sa1 = kv rows 32..63 (of this tile), col q = l32
        f32x16 sa0 = {}, sa1 = {};
        __builtin_amdgcn_s_setprio(1);
#pragma unroll
        for (int ks = 0; ks < 4; ks++) {
            int gx = (((ks * 2 + hi) ^ xs) * 8);
            bf16x8 ak0 = *(const bf16x8*)&Ks[cur][l32 * 64 + gx];
            bf16x8 ak1 = *(const bf16x8*)&Ks[cur][(32 + l32) * 64 + gx];
            sa0 = __builtin_amdgcn_mfma_f32_32x32x16_bf16(ak0, bq[ks], sa0, 0, 0, 0);
            sa1 = __builtin_amdgcn_mfma_f32_32x32x16_bf16(ak1, bq[ks], sa1, 0, 0, 0);
        }
        __builtin_amdgcn_s_setprio(0);

        // row max over 32 in-lane values + lane^32
        float mx = fmaxf(sa0[0], sa1[0]);
#pragma unroll
        for (int r = 1; r < 16; r++) mx = fmaxf(mx, fmaxf(sa0[r], sa1[r]));
        mx = fmaxf(mx, __shfl_xor(mx, 32));

        // defer-max: rescale only when max grew by > 8 (log2 units -> P <= 256)
        if (!__all(mx <= m_run + 8.0f)) {
            float mn = fmaxf(m_run, mx);
            float sc = __builtin_amdgcn_exp2f(m_run - mn);
            o0 *= sc; o1 *= sc;
            l_run *= sc;
            m_run = mn;
        }

        // P = exp2(S' - m_run) in place; row sum
        float rs = 0.f;
#pragma unroll
        for (int r = 0; r < 16; r++) { sa0[r] = __builtin_amdgcn_exp2f(sa0[r] - m_run); rs += sa0[r]; }
#pragma unroll
        for (int r = 0; r < 16; r++) { sa1[r] = __builtin_amdgcn_exp2f(sa1[r] - m_run); rs += sa1[r]; }
        rs += __shfl_xor(rs, 32);
        l_run += rs;

        // P -> PV B-frags: pack to bf16 pairs, half-swap lanes via v_permlane32_swap.
        // After swap, frag words are [a0,a1,b0,b1] for BOTH halves (derivation in notes).
        union BP { unsigned w[4]; bf16x8 v; };
        BP bpf[4];
#pragma unroll
        for (int ks = 0; ks < 4; ks++) {
            const f32x16& ps = (ks >> 1) ? sa1 : sa0;
            const int base = (ks & 1) * 8;
            unsigned a0 = pack_bf16(ps[base + 0], ps[base + 1]);
            unsigned a1 = pack_bf16(ps[base + 2], ps[base + 3]);
            unsigned b0 = pack_bf16(ps[base + 4], ps[base + 5]);
            unsigned b1 = pack_bf16(ps[base + 6], ps[base + 7]);
            asm volatile("v_permlane32_swap_b32 %0, %1" : "+v"(a0), "+v"(b0));
            asm volatile("v_permlane32_swap_b32 %0, %1" : "+v"(a1), "+v"(b1));
            bpf[ks].w[0] = a0; bpf[ks].w[1] = a1; bpf[ks].w[2] = b0; bpf[ks].w[3] = b1;
        }

        // O^T += V^T * P   (o0: d 0..31, o1: d 32..63)
        __builtin_amdgcn_s_setprio(1);
#pragma unroll
        for (int ks = 0; ks < 4; ks++) {
            int gx = (((ks * 2 + hi) ^ xs) * 8);
            bf16x8 av0 = *(const bf16x8*)&Vs[cur][l32 * 64 + gx];
            bf16x8 av1 = *(const bf16x8*)&Vs[cur][(32 + l32) * 64 + gx];
            o0 = __builtin_amdgcn_mfma_f32_32x32x16_bf16(av0, bpf[ks].v, o0, 0, 0, 0);
            o1 = __builtin_amdgcn_mfma_f32_32x32x16_bf16(av1, bpf[ks].v, o1, 0, 0, 0);
        }
        __builtin_amdgcn_s_setprio(0);
        __syncthreads();   // waves done with buf[cur]; staged loads drained
    }

    // epilogue: lane writes q-row q0+l32, d = dblk*32 + q2*8 + hi*4 + 0..3
    float inv = 1.0f / l_run;
    const int b = bh >> 4, h = bh & 15;
    unsigned short* orow = aout + ((size_t)b * SEQ + q0 + l32) * 1024 + h * 64;
#pragma unroll
    for (int dblk = 0; dblk < 2; dblk++) {
        const f32x16& oo = dblk ? o1 : o0;
#pragma unroll
        for (int q2 = 0; q2 < 4; q2++) {
            ushort4 u4;
            u4.x = f2bf(oo[q2 * 4 + 0] * inv);
            u4.y = f2bf(oo[q2 * 4 + 1] * inv);
            u4.z = f2bf(oo[q2 * 4 + 2] * inv);
            u4.w = f2bf(oo[q2 * 4 + 3] * inv);
            *(ushort4*)(orow + dblk * 32 + q2 * 8 + hi * 4) = u4;
        }
    }
}

extern "C" void kernel_launch(void* const* d_in, const int* in_sizes, int n_in,
                              void* d_out, int out_size, void* d_ws, size_t ws_size,
                              hipStream_t stream) {
    const float* x     = (const float*)d_in[0];
    const float* wqkv  = (const float*)d_in[1];
    const float* wproj = (const float*)d_in[2];
    const float* qg    = (const float*)d_in[3];
    const float* qb    = (const float*)d_in[4];
    const float* kg    = (const float*)d_in[5];
    const float* kb    = (const float*)d_in[6];
    float* out = (float*)d_out;

    char* ws = (char*)d_ws;
    unsigned short* xbf    = (unsigned short*)(ws);                       // 16 MB (reused for vT)
    unsigned short* wqkvT  = (unsigned short*)(ws + (16llu << 20));       // 6 MB
    unsigned short* wprojT = (unsigned short*)(ws + (22llu << 20));       // 2 MB
    unsigned short* qraw   = (unsigned short*)(ws + (24llu << 20));       // 16 MB
    unsigned short* kraw   = (unsigned short*)(ws + (40llu << 20));       // 16 MB
    unsigned short* vraw   = (unsigned short*)(ws + (56llu << 20));       // 16 MB
    unsigned short* aattn  = (unsigned short*)(ws + (72llu << 20));       // 16 MB (total 88 MB)
    unsigned short* vtr    = xbf;   // xbf dead after k_gemm<0>; reuse for vT

    hipLaunchKernelGGL(k_cvt_x, dim3(8192), dim3(256), 0, stream, (const float4*)x, (uint2*)xbf);
    hipLaunchKernelGGL(k_transpose, dim3(48, 16), dim3(256), 0, stream, wqkv, wqkvT, 3072);
    hipLaunchKernelGGL(k_transpose, dim3(16, 16), dim3(256), 0, stream, wproj, wprojT, 1024);
    hipLaunchKernelGGL((k_gemm<0>), dim3(64, 24), dim3(256), 0, stream, xbf, wqkvT, (float*)nullptr, qraw, kraw, vraw);
    hipLaunchKernelGGL(k_ln, dim3(32768, 2), dim3(256), 0, stream, qraw, kraw, qg, qb, kg, kb);
    hipLaunchKernelGGL(k_vtr, dim3(32, 64), dim3(256), 0, stream, vraw, vtr);
    hipLaunchKernelGGL(k_flash, dim3(64, 16), dim3(256), 0, stream, qraw, kraw, vtr, aattn);
    hipLaunchKernelGGL((k_gemm<1>), dim3(64, 8), dim3(256), 0, stream, aattn, wprojT, out,
                       (unsigned short*)nullptr, (unsigned short*)nullptr, (unsigned short*)nullptr);
}